// Round 12
// baseline (4045.471 us; speedup 1.0000x reference)
//
#include <hip/hip_runtime.h>

// ---------------------------------------------------------------------------
// v12 = v10 (best verified: 2727us; NO convoy barrier — r11 proved s_barrier
// forces a full waitcnt drain and regressed 283->383us) + ONE change:
// ci-PAIR batching in the j-loop.
//
// Why: VALUBusy 52% at ~6 waves/SIMD means correlated stalls — all waves
// drain at the same lgkmcnt(0) points (SMEM returns are out-of-order on
// CDNA -> compiler can only batch: issue a few j-groups' s_loads, wait 0,
// FMA, repeat). Stall cost is per WAIT-POINT, not per byte (P=2->4 lifted
// 37->52% by doubling FMAs/wait). Processing 2 ci per j-visit reads the
// 18 contiguous floats wt[(co*CIN+ci)*9 .. +18) in one wide s_load clump
// (same address formula as v10 — r7 showed changing it breaks look-ahead)
// and gives 144 FMA-cycles per wait-point. Cost: +18 tap VGPRs (~95 total,
// 5 waves/SIMD) — far cheaper than P=8's +64 acc VGPRs.
// Accumulation order per output element stays ci-ascending, t-ascending ->
// bitwise identical results.
//
// Dead ends measured this session (do not retry):
//  - LDS-staged weights (r4): ds_read issue overhead replaces scalar stall.
//  - [co_blk][ci][j][9] repack (r7): breaks compiler s_load look-ahead.
//  - 2-deep tap prefetch (r3/r9): VGPR cost cuts waves; TLP > ILP here.
//  - k4+pixconv fusion (r8): +131us/image; k4 output is L2/L3-resident.
//  - convoy __syncthreads (r11): barrier = full waitcnt drain, -35%.
// ---------------------------------------------------------------------------

// ---------------------------------------------------------------------------
// Direct 3x3 SAME conv + ReLU, fp32, row-range aware.
// Block: 256 threads = 64-wide x (4*P)-tall tile. Thread (lx, yg) owns P
// output rows at column x; CB outputs in VGPRs. No LDS, no barriers.
// Per ci-pair: 6*(P+2) global taps, then CB j-groups of 18 contiguous
// s_load weights feeding 2*P*9 fmac each.
// ---------------------------------------------------------------------------
template<int CIN, int COUT, int CB, int P, int W>
__global__ __launch_bounds__(256, 2) void conv3x3_relu_k(
    const float* __restrict__ in, const float* __restrict__ wt,
    float* __restrict__ out,
    int in_y0, int in_rows, int out_y0, int out_rows)
{
  static_assert(COUT % CB == 0, "CB must divide COUT");
  static_assert(CIN == 1 || CIN % 2 == 0, "CIN must be 1 or even");
  constexpr int NCB = COUT / CB;
  constexpr int TW  = 64;
  constexpr int TH  = 4 * P;

  const int n   = blockIdx.z / NCB;           // image index
  const int co0 = (blockIdx.z % NCB) * CB;
  const int lx  = threadIdx.x & 63;
  const int yg  = threadIdx.x >> 6;
  const int x0  = blockIdx.x * TW;
  const int x   = x0 + lx;
  const int oy0 = out_y0 + blockIdx.y * TH;   // image row of tile top
  const int yb  = yg * P;

  const int maxoff = in_rows * W * 4 - 4;     // last valid byte offset in chan

  // ---- per-thread tap offsets + masks (constant across ci) ----
  int   voff[P + 2][3];
  float mrow[P + 2];
#pragma unroll
  for (int r = 0; r < P + 2; ++r) {
    int ry = oy0 + yb + r - 1 - in_y0;        // buffer-relative row
    mrow[r] = (ry >= 0 && ry < in_rows) ? 1.f : 0.f;
    int ryc = ry < 0 ? 0 : (ry >= in_rows ? in_rows - 1 : ry);
    int vo  = (ryc * W + x) * 4;
    voff[r][1] = vo;
    voff[r][0] = (vo > 4 ? vo : 4) - 4;       // clamped left tap, never < 0
    int vr = vo + 4;
    voff[r][2] = vr < maxoff ? vr : maxoff;   // clamped right tap, in-bounds
  }
  const float ml = (x == 0)     ? 0.f : 1.f;
  const float mr = (x == W - 1) ? 0.f : 1.f;

  const bool interior =
      (x0 > 0) && (x0 + TW < W) &&
      ((oy0 - 1 - in_y0) >= 0) && ((oy0 + TH - in_y0) < in_rows);

  float acc[CB][P];
#pragma unroll
  for (int j = 0; j < CB; ++j)
#pragma unroll
    for (int p = 0; p < P; ++p) acc[j][p] = 0.f;

  const float* inN = in + (size_t)n * CIN * in_rows * W;   // uniform -> SGPR
  const size_t chbytes = (size_t)in_rows * W * 4;

  if constexpr (CIN == 1) {
    // ---- single-channel path (e1/k1) ----
    const char* bp = (const char*)inN;
    float va[P + 2][3];
#pragma unroll
    for (int r = 0; r < P + 2; ++r)
#pragma unroll
      for (int c = 0; c < 3; ++c)
        va[r][c] = *(const float*)(bp + voff[r][c]);
    if (!interior) {
#pragma unroll
      for (int r = 0; r < P + 2; ++r)
#pragma unroll
        for (int c = 0; c < 3; ++c) {
          float m = mrow[r];
          if (c == 0) m *= ml;
          if (c == 2) m *= mr;
          va[r][c] *= m;
        }
    }
#pragma unroll
    for (int j = 0; j < CB; ++j) {
      const float* wp = wt + (size_t)(co0 + j) * 9;
      float w[9];
#pragma unroll
      for (int t = 0; t < 9; ++t) w[t] = wp[t];
#pragma unroll
      for (int t = 0; t < 9; ++t) {
        const int r = t / 3, c = t - r * 3;
#pragma unroll
        for (int p = 0; p < P; ++p)
          acc[j][p] = fmaf(va[p + r][c], w[t], acc[j][p]);
      }
    }
  } else {
    // ---- ci-pair path: 2 channels per j-visit, 18-float weight clump ----
#pragma unroll 1
    for (int ci = 0; ci < CIN; ci += 2) {
      const char* bp0 = (const char*)inN + (size_t)ci * chbytes;
      const char* bp1 = bp0 + chbytes;

      float va0[P + 2][3], va1[P + 2][3];
#pragma unroll
      for (int r = 0; r < P + 2; ++r)
#pragma unroll
        for (int c = 0; c < 3; ++c) {
          va0[r][c] = *(const float*)(bp0 + voff[r][c]);
          va1[r][c] = *(const float*)(bp1 + voff[r][c]);
        }

      if (!interior) {                        // block-uniform branch
#pragma unroll
        for (int r = 0; r < P + 2; ++r)
#pragma unroll
          for (int c = 0; c < 3; ++c) {
            float m = mrow[r];
            if (c == 0) m *= ml;
            if (c == 2) m *= mr;
            va0[r][c] *= m;
            va1[r][c] *= m;
          }
      }

#pragma unroll
      for (int j = 0; j < CB; ++j) {
        // 18 contiguous floats: weights for (co0+j, ci) and (co0+j, ci+1).
        // Same base formula as v10 (keeps compiler s_load look-ahead).
        const float* wp = wt + ((size_t)(co0 + j) * CIN + ci) * 9;
        float w[18];
#pragma unroll
        for (int t = 0; t < 18; ++t) w[t] = wp[t];
#pragma unroll
        for (int t = 0; t < 9; ++t) {
          const int r = t / 3, c = t - r * 3;
#pragma unroll
          for (int p = 0; p < P; ++p)
            acc[j][p] = fmaf(va0[p + r][c], w[t], acc[j][p]);
        }
#pragma unroll
        for (int t = 0; t < 9; ++t) {
          const int r = t / 3, c = t - r * 3;
#pragma unroll
          for (int p = 0; p < P; ++p)
            acc[j][p] = fmaf(va1[p + r][c], w[9 + t], acc[j][p]);
        }
      }
    }
  }

  // ---- epilogue: ReLU + store ----
  float* outN = out + (size_t)n * COUT * out_rows * W;
#pragma unroll
  for (int p = 0; p < P; ++p) {
    const int orow = (oy0 + yb + p) - out_y0;
    if (orow < out_rows) {
#pragma unroll
      for (int j = 0; j < CB; ++j) {
        float v = acc[j][p] < 0.f ? 0.f : acc[j][p];
        outN[((size_t)(co0 + j) * out_rows + orow) * W + x] = v;
      }
    }
  }
}

// ---------------------------------------------------------------------------
// PixelShuffle r=4 + ReLU, BOTH images: (2,16,256,256) -> (2,1024,1024)
// out[n, 4*hh+ii, 4*ww+jj] = in[n, ii*4+jj, hh, ww]
// ---------------------------------------------------------------------------
__global__ __launch_bounds__(256) void pixel_shuffle_relu_k(
    const float* __restrict__ in, float* __restrict__ out)
{
  int i = blockIdx.x * 256 + threadIdx.x;      // over 2*1024*1024
  int n = i >> 20;
  int p = i & 1048575;
  int x = p & 1023, y = p >> 10;
  int c = (y & 3) * 4 + (x & 3);
  float v = in[((size_t)(n * 16 + c) * 256 + (y >> 2)) * 256 + (x >> 2)];
  out[i] = v < 0.f ? 0.f : v;
}

// ---------------------------------------------------------------------------
// Per-pixel 5x5 dynamic conv + residual, one image, one row-strip:
// out[y,x] = h[y,x] + sum_{kw,kh} h_pad[y+kh-2, x+kw-2] * ker[kw*5+kh, y, x]
// ker holds rows [ky0, ky0+krows) of the image (channel stride krows*1024).
// ---------------------------------------------------------------------------
__global__ __launch_bounds__(256) void pixel_conv_add_k(
    const float* __restrict__ h,    // full image (1024,1024)
    const float* __restrict__ ker,  // (25, krows, 1024)
    float* __restrict__ out,        // full image (1024,1024)
    int ky0, int krows)
{
  const int tx = threadIdx.x & 15, ty = threadIdx.x >> 4;
  const int x0 = blockIdx.x * 16;
  const int y0 = ky0 + blockIdx.y * 16;

  __shared__ float tile[20][21];
  for (int t = threadIdx.x; t < 20 * 20; t += 256) {
    int r = t / 20, c = t - r * 20;
    int yy = y0 + r - 2, xx = x0 + c - 2;
    float v = 0.f;
    if (yy >= 0 && yy < 1024 && xx >= 0 && xx < 1024) v = h[(size_t)yy * 1024 + xx];
    tile[r][c] = v;
  }
  __syncthreads();

  const int x = x0 + tx, y = y0 + ty;
  float acc = tile[ty + 2][tx + 2];            // residual h
  const size_t kpix = (size_t)(y - ky0) * 1024 + x;
#pragma unroll
  for (int kw = 0; kw < 5; ++kw) {
#pragma unroll
    for (int kh = 0; kh < 5; ++kh) {
      float kv = ker[(size_t)(kw * 5 + kh) * krows * 1024 + kpix];
      acc = fmaf(tile[ty + kh][tx + kw], kv, acc);
    }
  }
  out[(size_t)y * 1024 + x] = acc;
}

// ---------------------------------------------------------------------------
// Launch. Workspace (adaptive to ws_size):
//   Hs: 8 MiB  — shuffled h, both images, persists
//   A : max(32ch*(S+6)*1024*4, 16.8 MB)  — z1/z3 strip buf; encoder ping (2 img)
//   B : max(64ch*(S+4)*1024*4, 33.6 MB)  — z2/z4 strip buf; encoder pong (2 img)
// S = largest of {1024,512,256,128,64} fitting ws_size.
// Encoder/decoder batches BOTH images per dispatch.
// z-branch runs per image in row strips of height S with halo-recompute
// (identical numerics to full-image conv).
// ---------------------------------------------------------------------------
extern "C" void kernel_launch(void* const* d_in, const int* in_sizes, int n_in,
                              void* d_out, int out_size, void* d_ws, size_t ws_size,
                              hipStream_t stream) {
  const float* x    = (const float*)d_in[0];
  const float* w_e1 = (const float*)d_in[1];
  const float* w_e2 = (const float*)d_in[2];
  const float* w_e3 = (const float*)d_in[3];
  const float* w_d1 = (const float*)d_in[4];
  const float* w_d2 = (const float*)d_in[5];
  const float* w_k1 = (const float*)d_in[6];
  const float* w_k2 = (const float*)d_in[7];
  const float* w_k3 = (const float*)d_in[8];
  const float* w_k4 = (const float*)d_in[9];

  const size_t HS_SZ = 8388608;                 // 2 * 1024*1024 * 4
  const size_t AMIN  = 16777216;                // 2 img * 32ch @256²
  const size_t BMIN  = 33554432;                // 2 img * 64ch @256²

  int S = 64;
  {
    const int cand[5] = {1024, 512, 256, 128, 64};
    for (int i = 0; i < 5; ++i) {
      int s = cand[i];
      size_t a = 32ull * (size_t)(s + 6) * 1024 * 4; if (a < AMIN) a = AMIN;
      size_t b = 64ull * (size_t)(s + 4) * 1024 * 4; if (b < BMIN) b = BMIN;
      if (HS_SZ + a + b <= ws_size) { S = s; break; }
    }
  }
  size_t A_SZ = 32ull * (size_t)(S + 6) * 1024 * 4; if (A_SZ < AMIN) A_SZ = AMIN;

  char* ws = (char*)d_ws;
  float* Hs = (float*)(ws);
  float* A  = (float*)(ws + HS_SZ);
  float* B  = (float*)(ws + HS_SZ + A_SZ);
  float* outp = (float*)d_out;

  dim3 blk(256);

  // ---- encoder/decoder @256², both images per dispatch, ping-pong A<->B ----
  // P=4 -> TH=16. grid: (256/64, 256/16, 2*NCB)
  conv3x3_relu_k<1, 16, 16, 4, 256><<<dim3(4, 16, 2), blk, 0, stream>>>(x, w_e1, B, 0, 256, 0, 256);
  conv3x3_relu_k<16, 32, 16, 4, 256><<<dim3(4, 16, 4), blk, 0, stream>>>(B, w_e2, A, 0, 256, 0, 256);
  conv3x3_relu_k<32, 64, 16, 4, 256><<<dim3(4, 16, 8), blk, 0, stream>>>(A, w_e3, B, 0, 256, 0, 256);
  conv3x3_relu_k<64, 32, 16, 4, 256><<<dim3(4, 16, 4), blk, 0, stream>>>(B, w_d1, A, 0, 256, 0, 256);
  conv3x3_relu_k<32, 16, 16, 4, 256><<<dim3(4, 16, 2), blk, 0, stream>>>(A, w_d2, B, 0, 256, 0, 256);
  pixel_shuffle_relu_k<<<dim3(8192), blk, 0, stream>>>(B, Hs);

  // ---- kernel-prediction branch + dynamic conv, per image, row strips ----
  const int nstr = 1024 / S;
  for (int n = 0; n < 2; ++n) {
    const float* himg = Hs + (size_t)n * 1048576;
    float* outn = outp + (size_t)n * 1048576;
    for (int s = 0; s < nstr; ++s) {
      const int r0 = s * S, r1 = r0 + S;
      const int z1y0 = (r0 - 3 > 0) ? r0 - 3 : 0;
      const int z1r  = ((r1 + 3 < 1024) ? r1 + 3 : 1024) - z1y0;
      const int z2y0 = (r0 - 2 > 0) ? r0 - 2 : 0;
      const int z2r  = ((r1 + 2 < 1024) ? r1 + 2 : 1024) - z2y0;
      const int z3y0 = (r0 - 1 > 0) ? r0 - 1 : 0;
      const int z3r  = ((r1 + 1 < 1024) ? r1 + 1 : 1024) - z3y0;
      const int g1 = (z1r + 15) / 16, g2 = (z2r + 15) / 16, g3 = (z3r + 15) / 16;

      conv3x3_relu_k<1, 32, 16, 4, 1024><<<dim3(16, g1, 2), blk, 0, stream>>>(
          himg, w_k1, A, 0, 1024, z1y0, z1r);
      conv3x3_relu_k<32, 64, 16, 4, 1024><<<dim3(16, g2, 4), blk, 0, stream>>>(
          A, w_k2, B, z1y0, z1r, z2y0, z2r);
      conv3x3_relu_k<64, 32, 16, 4, 1024><<<dim3(16, g3, 2), blk, 0, stream>>>(
          B, w_k3, A, z2y0, z2r, z3y0, z3r);
      conv3x3_relu_k<32, 25, 25, 4, 1024><<<dim3(16, S / 16, 1), blk, 0, stream>>>(
          A, w_k4, B, z3y0, z3r, r0, S);
      pixel_conv_add_k<<<dim3(64, S / 16), blk, 0, stream>>>(
          himg, B, outn, r0, S);
    }
  }
}

// Round 13
// 2927.226 us; speedup vs baseline: 1.3820x; 1.3820x over previous
//
#include <hip/hip_runtime.h>

// ---------------------------------------------------------------------------
// v13 = v10 (best verified: 2727us) + ONE change: P=4 -> P=6 on all CB=16
// convs (k4 stays CB=25/P=4).
//
// Why P=6: waves/SIMD is a step function of VGPR (halves at 64/128/256).
// v10 sits at 76 VGPR — mid-band. P=6 adds ~38 VGPRs -> ~114, still <128:
// SAME 4 waves/SIMD, but 108 FMA-cycles per scalar weight fetch instead of
// 72 (+50% on the r6-verified lever). Does NOT touch the weight-path code
// shape (r7/r12 proved changing it breaks compiler s_load look-ahead).
//
// Dead ends measured this session (do not retry):
//  - LDS-staged weights (r4): ds_read issue overhead replaces scalar stall.
//  - [co_blk][ci][j][9] repack (r7) / ci-pair w[18] clump (r12): both break
//    s_load look-ahead (SGPR 80->64), VALUBusy -> 23-28%.
//  - 2-deep tap prefetch (r3/r9): VGPR/dependency cost; TLP > ILP here.
//  - k4+pixconv fusion (r8): +131us/image; k4 output is L2/L3-resident.
//  - convoy __syncthreads (r11): barrier = full waitcnt drain, -35%.
// ---------------------------------------------------------------------------

// ---------------------------------------------------------------------------
// Direct 3x3 SAME conv + ReLU, fp32, row-range aware (v6 core, proven):
// no LDS, no barriers. Block: 256 threads = 64-wide x (4*P)-tall tile.
// Thread (lx, yg) owns P output rows at column x; CB outputs in VGPRs.
// Per ci: 3*(P+2) global taps (voffsets computed once; L1/L2-resident),
// then CB j-groups of 9 wave-uniform s_load weights feeding P*9 fmac each
// (compiler packs p-pairs into v_pk_fma_f32).
// ---------------------------------------------------------------------------
template<int CIN, int COUT, int CB, int P, int W>
__global__ __launch_bounds__(256, 2) void conv3x3_relu_k(
    const float* __restrict__ in, const float* __restrict__ wt,
    float* __restrict__ out,
    int in_y0, int in_rows, int out_y0, int out_rows)
{
  static_assert(COUT % CB == 0, "CB must divide COUT");
  constexpr int NCB = COUT / CB;
  constexpr int TW  = 64;
  constexpr int TH  = 4 * P;

  const int n   = blockIdx.z / NCB;           // image index
  const int co0 = (blockIdx.z % NCB) * CB;
  const int lx  = threadIdx.x & 63;
  const int yg  = threadIdx.x >> 6;
  const int x0  = blockIdx.x * TW;
  const int x   = x0 + lx;
  const int oy0 = out_y0 + blockIdx.y * TH;   // image row of tile top
  const int yb  = yg * P;

  const int maxoff = in_rows * W * 4 - 4;     // last valid byte offset in chan

  // ---- per-thread tap offsets + masks (constant across ci) ----
  int   voff[P + 2][3];
  float mrow[P + 2];
#pragma unroll
  for (int r = 0; r < P + 2; ++r) {
    int ry = oy0 + yb + r - 1 - in_y0;        // buffer-relative row
    mrow[r] = (ry >= 0 && ry < in_rows) ? 1.f : 0.f;
    int ryc = ry < 0 ? 0 : (ry >= in_rows ? in_rows - 1 : ry);
    int vo  = (ryc * W + x) * 4;
    voff[r][1] = vo;
    voff[r][0] = (vo > 4 ? vo : 4) - 4;       // clamped left tap, never < 0
    int vr = vo + 4;
    voff[r][2] = vr < maxoff ? vr : maxoff;   // clamped right tap, in-bounds
  }
  const float ml = (x == 0)     ? 0.f : 1.f;
  const float mr = (x == W - 1) ? 0.f : 1.f;

  const bool interior =
      (x0 > 0) && (x0 + TW < W) &&
      ((oy0 - 1 - in_y0) >= 0) && ((oy0 + TH - in_y0) < in_rows);

  float acc[CB][P];
#pragma unroll
  for (int j = 0; j < CB; ++j)
#pragma unroll
    for (int p = 0; p < P; ++p) acc[j][p] = 0.f;

  const float* inN = in + (size_t)n * CIN * in_rows * W;   // uniform -> SGPR
  const size_t chbytes = (size_t)in_rows * W * 4;

#pragma unroll 1
  for (int ci = 0; ci < CIN; ++ci) {
    const char* bp = (const char*)inN + (size_t)ci * chbytes;  // scalar step

    float va[P + 2][3];
#pragma unroll
    for (int r = 0; r < P + 2; ++r)
#pragma unroll
      for (int c = 0; c < 3; ++c)
        va[r][c] = *(const float*)(bp + voff[r][c]);

    if (!interior) {                          // block-uniform branch
#pragma unroll
      for (int r = 0; r < P + 2; ++r) {
#pragma unroll
        for (int c = 0; c < 3; ++c) {
          float m = mrow[r];
          if (c == 0) m *= ml;
          if (c == 2) m *= mr;
          va[r][c] *= m;
        }
      }
    }

#pragma unroll
    for (int j = 0; j < CB; ++j) {
      const float* wp = wt + ((size_t)(co0 + j) * CIN + ci) * 9;  // uniform
      float w[9];
#pragma unroll
      for (int t = 0; t < 9; ++t) w[t] = wp[t];
#pragma unroll
      for (int t = 0; t < 9; ++t) {
        const int r = t / 3, c = t - r * 3;
#pragma unroll
        for (int p = 0; p < P; ++p)           // p-interleave: indep chains
          acc[j][p] = fmaf(va[p + r][c], w[t], acc[j][p]);
      }
    }
  }

  // ---- epilogue: ReLU + store ----
  float* outN = out + (size_t)n * COUT * out_rows * W;
#pragma unroll
  for (int p = 0; p < P; ++p) {
    const int orow = (oy0 + yb + p) - out_y0;
    if (orow < out_rows) {
#pragma unroll
      for (int j = 0; j < CB; ++j) {
        float v = acc[j][p] < 0.f ? 0.f : acc[j][p];
        outN[((size_t)(co0 + j) * out_rows + orow) * W + x] = v;
      }
    }
  }
}

// ---------------------------------------------------------------------------
// PixelShuffle r=4 + ReLU, BOTH images: (2,16,256,256) -> (2,1024,1024)
// out[n, 4*hh+ii, 4*ww+jj] = in[n, ii*4+jj, hh, ww]
// ---------------------------------------------------------------------------
__global__ __launch_bounds__(256) void pixel_shuffle_relu_k(
    const float* __restrict__ in, float* __restrict__ out)
{
  int i = blockIdx.x * 256 + threadIdx.x;      // over 2*1024*1024
  int n = i >> 20;
  int p = i & 1048575;
  int x = p & 1023, y = p >> 10;
  int c = (y & 3) * 4 + (x & 3);
  float v = in[((size_t)(n * 16 + c) * 256 + (y >> 2)) * 256 + (x >> 2)];
  out[i] = v < 0.f ? 0.f : v;
}

// ---------------------------------------------------------------------------
// Per-pixel 5x5 dynamic conv + residual, one image, one row-strip:
// out[y,x] = h[y,x] + sum_{kw,kh} h_pad[y+kh-2, x+kw-2] * ker[kw*5+kh, y, x]
// ker holds rows [ky0, ky0+krows) of the image (channel stride krows*1024).
// ---------------------------------------------------------------------------
__global__ __launch_bounds__(256) void pixel_conv_add_k(
    const float* __restrict__ h,    // full image (1024,1024)
    const float* __restrict__ ker,  // (25, krows, 1024)
    float* __restrict__ out,        // full image (1024,1024)
    int ky0, int krows)
{
  const int tx = threadIdx.x & 15, ty = threadIdx.x >> 4;
  const int x0 = blockIdx.x * 16;
  const int y0 = ky0 + blockIdx.y * 16;

  __shared__ float tile[20][21];
  for (int t = threadIdx.x; t < 20 * 20; t += 256) {
    int r = t / 20, c = t - r * 20;
    int yy = y0 + r - 2, xx = x0 + c - 2;
    float v = 0.f;
    if (yy >= 0 && yy < 1024 && xx >= 0 && xx < 1024) v = h[(size_t)yy * 1024 + xx];
    tile[r][c] = v;
  }
  __syncthreads();

  const int x = x0 + tx, y = y0 + ty;
  float acc = tile[ty + 2][tx + 2];            // residual h
  const size_t kpix = (size_t)(y - ky0) * 1024 + x;
#pragma unroll
  for (int kw = 0; kw < 5; ++kw) {
#pragma unroll
    for (int kh = 0; kh < 5; ++kh) {
      float kv = ker[(size_t)(kw * 5 + kh) * krows * 1024 + kpix];
      acc = fmaf(tile[ty + kh][tx + kw], kv, acc);
    }
  }
  out[(size_t)y * 1024 + x] = acc;
}

// ---------------------------------------------------------------------------
// Launch. Workspace (adaptive to ws_size):
//   Hs: 8 MiB  — shuffled h, both images, persists
//   A : max(32ch*(S+6)*1024*4, 16.8 MB)  — z1/z3 strip buf; encoder ping (2 img)
//   B : max(64ch*(S+4)*1024*4, 33.6 MB)  — z2/z4 strip buf; encoder pong (2 img)
// S = largest of {1024,512,256,128,64} fitting ws_size.
// Encoder/decoder batches BOTH images per dispatch.
// z-branch runs per image in row strips of height S with halo-recompute
// (identical numerics to full-image conv).
// ---------------------------------------------------------------------------
extern "C" void kernel_launch(void* const* d_in, const int* in_sizes, int n_in,
                              void* d_out, int out_size, void* d_ws, size_t ws_size,
                              hipStream_t stream) {
  const float* x    = (const float*)d_in[0];
  const float* w_e1 = (const float*)d_in[1];
  const float* w_e2 = (const float*)d_in[2];
  const float* w_e3 = (const float*)d_in[3];
  const float* w_d1 = (const float*)d_in[4];
  const float* w_d2 = (const float*)d_in[5];
  const float* w_k1 = (const float*)d_in[6];
  const float* w_k2 = (const float*)d_in[7];
  const float* w_k3 = (const float*)d_in[8];
  const float* w_k4 = (const float*)d_in[9];

  const size_t HS_SZ = 8388608;                 // 2 * 1024*1024 * 4
  const size_t AMIN  = 16777216;                // 2 img * 32ch @256²
  const size_t BMIN  = 33554432;                // 2 img * 64ch @256²

  int S = 64;
  {
    const int cand[5] = {1024, 512, 256, 128, 64};
    for (int i = 0; i < 5; ++i) {
      int s = cand[i];
      size_t a = 32ull * (size_t)(s + 6) * 1024 * 4; if (a < AMIN) a = AMIN;
      size_t b = 64ull * (size_t)(s + 4) * 1024 * 4; if (b < BMIN) b = BMIN;
      if (HS_SZ + a + b <= ws_size) { S = s; break; }
    }
  }
  size_t A_SZ = 32ull * (size_t)(S + 6) * 1024 * 4; if (A_SZ < AMIN) A_SZ = AMIN;

  char* ws = (char*)d_ws;
  float* Hs = (float*)(ws);
  float* A  = (float*)(ws + HS_SZ);
  float* B  = (float*)(ws + HS_SZ + A_SZ);
  float* outp = (float*)d_out;

  dim3 blk(256);

  // ---- encoder/decoder @256², both images per dispatch, ping-pong A<->B ----
  // P=6 -> TH=24. grid: (256/64, ceil(256/24)=11, 2*NCB); tail rows masked.
  conv3x3_relu_k<1, 16, 16, 6, 256><<<dim3(4, 11, 2), blk, 0, stream>>>(x, w_e1, B, 0, 256, 0, 256);
  conv3x3_relu_k<16, 32, 16, 6, 256><<<dim3(4, 11, 4), blk, 0, stream>>>(B, w_e2, A, 0, 256, 0, 256);
  conv3x3_relu_k<32, 64, 16, 6, 256><<<dim3(4, 11, 8), blk, 0, stream>>>(A, w_e3, B, 0, 256, 0, 256);
  conv3x3_relu_k<64, 32, 16, 6, 256><<<dim3(4, 11, 4), blk, 0, stream>>>(B, w_d1, A, 0, 256, 0, 256);
  conv3x3_relu_k<32, 16, 16, 6, 256><<<dim3(4, 11, 2), blk, 0, stream>>>(A, w_d2, B, 0, 256, 0, 256);
  pixel_shuffle_relu_k<<<dim3(8192), blk, 0, stream>>>(B, Hs);

  // ---- kernel-prediction branch + dynamic conv, per image, row strips ----
  const int nstr = 1024 / S;
  for (int n = 0; n < 2; ++n) {
    const float* himg = Hs + (size_t)n * 1048576;
    float* outn = outp + (size_t)n * 1048576;
    for (int s = 0; s < nstr; ++s) {
      const int r0 = s * S, r1 = r0 + S;
      const int z1y0 = (r0 - 3 > 0) ? r0 - 3 : 0;
      const int z1r  = ((r1 + 3 < 1024) ? r1 + 3 : 1024) - z1y0;
      const int z2y0 = (r0 - 2 > 0) ? r0 - 2 : 0;
      const int z2r  = ((r1 + 2 < 1024) ? r1 + 2 : 1024) - z2y0;
      const int z3y0 = (r0 - 1 > 0) ? r0 - 1 : 0;
      const int z3r  = ((r1 + 1 < 1024) ? r1 + 1 : 1024) - z3y0;
      const int g1 = (z1r + 23) / 24, g2 = (z2r + 23) / 24, g3 = (z3r + 23) / 24;

      conv3x3_relu_k<1, 32, 16, 6, 1024><<<dim3(16, g1, 2), blk, 0, stream>>>(
          himg, w_k1, A, 0, 1024, z1y0, z1r);
      conv3x3_relu_k<32, 64, 16, 6, 1024><<<dim3(16, g2, 4), blk, 0, stream>>>(
          A, w_k2, B, z1y0, z1r, z2y0, z2r);
      conv3x3_relu_k<64, 32, 16, 6, 1024><<<dim3(16, g3, 2), blk, 0, stream>>>(
          B, w_k3, A, z2y0, z2r, z3y0, z3r);
      conv3x3_relu_k<32, 25, 25, 4, 1024><<<dim3(16, S / 16, 1), blk, 0, stream>>>(
          A, w_k4, B, z3y0, z3r, r0, S);
      pixel_conv_add_k<<<dim3(64, S / 16), blk, 0, stream>>>(
          himg, B, outn, r0, S);
    }
  }
}

// Round 14
// 2698.014 us; speedup vs baseline: 1.4994x; 1.0850x over previous
//
#include <hip/hip_runtime.h>

// ---------------------------------------------------------------------------
// v14 = v10 (best verified: 2727us) + ONE change: s_setprio(1) around the
// FMA cluster (j-loop), setprio(0) during the tap-load phase.
//
// Why: no barriers -> 6 waves/SIMD free-run with natural phase diversity
// ({tap-load | FMA} phases). setprio lets FMA-ready waves win issue
// arbitration over waves issuing memory ops (technique proven +4-7% on
// free-running attn waves; null only on barrier-lockstep kernels — ours
// is not). Zero register / numeric / code-shape change to either memory
// path, so it cannot trigger the s_load look-ahead breakage mode.
//
// Dead ends measured this session (do not retry):
//  - LDS-staged weights (r4): ds_read issue overhead replaces scalar stall.
//  - [co_blk][ci][j][9] repack (r7) / ci-pair w[18] clump (r12): both break
//    s_load look-ahead (SGPR 80->64), VALUBusy -> 23-28%.
//  - 2-deep tap prefetch (r3/r9): VGPR/dependency cost; TLP > ILP here.
//  - k4+pixconv fusion (r8): +131us/image; k4 output is L2/L3-resident.
//  - convoy __syncthreads (r11): barrier = full waitcnt drain, -35%.
//  - P=6 (r13): VGPR 104 -> 4 waves/SIMD (occupancy 24->16), VALUBusy 46%.
//    76-VGPR/6-wave is the TLP sweet spot; the P-lever ends at P=4.
// ---------------------------------------------------------------------------

// ---------------------------------------------------------------------------
// Direct 3x3 SAME conv + ReLU, fp32, row-range aware (v6 core, proven):
// no LDS, no barriers. Block: 256 threads = 64-wide x (4*P)-tall tile.
// Thread (lx, yg) owns P output rows at column x; CB outputs in VGPRs.
// Per ci: 3*(P+2) global taps (voffsets computed once; L1/L2-resident),
// then CB j-groups of 9 wave-uniform s_load weights feeding P*9 fmac each
// (compiler packs p-pairs into v_pk_fma_f32).
// ---------------------------------------------------------------------------
template<int CIN, int COUT, int CB, int P, int W>
__global__ __launch_bounds__(256, 2) void conv3x3_relu_k(
    const float* __restrict__ in, const float* __restrict__ wt,
    float* __restrict__ out,
    int in_y0, int in_rows, int out_y0, int out_rows)
{
  static_assert(COUT % CB == 0, "CB must divide COUT");
  constexpr int NCB = COUT / CB;
  constexpr int TW  = 64;
  constexpr int TH  = 4 * P;

  const int n   = blockIdx.z / NCB;           // image index
  const int co0 = (blockIdx.z % NCB) * CB;
  const int lx  = threadIdx.x & 63;
  const int yg  = threadIdx.x >> 6;
  const int x0  = blockIdx.x * TW;
  const int x   = x0 + lx;
  const int oy0 = out_y0 + blockIdx.y * TH;   // image row of tile top
  const int yb  = yg * P;

  const int maxoff = in_rows * W * 4 - 4;     // last valid byte offset in chan

  // ---- per-thread tap offsets + masks (constant across ci) ----
  int   voff[P + 2][3];
  float mrow[P + 2];
#pragma unroll
  for (int r = 0; r < P + 2; ++r) {
    int ry = oy0 + yb + r - 1 - in_y0;        // buffer-relative row
    mrow[r] = (ry >= 0 && ry < in_rows) ? 1.f : 0.f;
    int ryc = ry < 0 ? 0 : (ry >= in_rows ? in_rows - 1 : ry);
    int vo  = (ryc * W + x) * 4;
    voff[r][1] = vo;
    voff[r][0] = (vo > 4 ? vo : 4) - 4;       // clamped left tap, never < 0
    int vr = vo + 4;
    voff[r][2] = vr < maxoff ? vr : maxoff;   // clamped right tap, in-bounds
  }
  const float ml = (x == 0)     ? 0.f : 1.f;
  const float mr = (x == W - 1) ? 0.f : 1.f;

  const bool interior =
      (x0 > 0) && (x0 + TW < W) &&
      ((oy0 - 1 - in_y0) >= 0) && ((oy0 + TH - in_y0) < in_rows);

  float acc[CB][P];
#pragma unroll
  for (int j = 0; j < CB; ++j)
#pragma unroll
    for (int p = 0; p < P; ++p) acc[j][p] = 0.f;

  const float* inN = in + (size_t)n * CIN * in_rows * W;   // uniform -> SGPR
  const size_t chbytes = (size_t)in_rows * W * 4;

#pragma unroll 1
  for (int ci = 0; ci < CIN; ++ci) {
    const char* bp = (const char*)inN + (size_t)ci * chbytes;  // scalar step

    float va[P + 2][3];
#pragma unroll
    for (int r = 0; r < P + 2; ++r)
#pragma unroll
      for (int c = 0; c < 3; ++c)
        va[r][c] = *(const float*)(bp + voff[r][c]);

    if (!interior) {                          // block-uniform branch
#pragma unroll
      for (int r = 0; r < P + 2; ++r) {
#pragma unroll
        for (int c = 0; c < 3; ++c) {
          float m = mrow[r];
          if (c == 0) m *= ml;
          if (c == 2) m *= mr;
          va[r][c] *= m;
        }
      }
    }

    // FMA phase: boost this wave in issue arbitration over waves that are
    // still issuing tap/weight loads (free-running phase diversity).
    __builtin_amdgcn_s_setprio(1);
#pragma unroll
    for (int j = 0; j < CB; ++j) {
      const float* wp = wt + ((size_t)(co0 + j) * CIN + ci) * 9;  // uniform
      float w[9];
#pragma unroll
      for (int t = 0; t < 9; ++t) w[t] = wp[t];
#pragma unroll
      for (int t = 0; t < 9; ++t) {
        const int r = t / 3, c = t - r * 3;
#pragma unroll
        for (int p = 0; p < P; ++p)           // p-interleave: indep chains
          acc[j][p] = fmaf(va[p + r][c], w[t], acc[j][p]);
      }
    }
    __builtin_amdgcn_s_setprio(0);
  }

  // ---- epilogue: ReLU + store ----
  float* outN = out + (size_t)n * COUT * out_rows * W;
#pragma unroll
  for (int p = 0; p < P; ++p) {
    const int orow = (oy0 + yb + p) - out_y0;
    if (orow < out_rows) {
#pragma unroll
      for (int j = 0; j < CB; ++j) {
        float v = acc[j][p] < 0.f ? 0.f : acc[j][p];
        outN[((size_t)(co0 + j) * out_rows + orow) * W + x] = v;
      }
    }
  }
}

// ---------------------------------------------------------------------------
// PixelShuffle r=4 + ReLU, BOTH images: (2,16,256,256) -> (2,1024,1024)
// out[n, 4*hh+ii, 4*ww+jj] = in[n, ii*4+jj, hh, ww]
// ---------------------------------------------------------------------------
__global__ __launch_bounds__(256) void pixel_shuffle_relu_k(
    const float* __restrict__ in, float* __restrict__ out)
{
  int i = blockIdx.x * 256 + threadIdx.x;      // over 2*1024*1024
  int n = i >> 20;
  int p = i & 1048575;
  int x = p & 1023, y = p >> 10;
  int c = (y & 3) * 4 + (x & 3);
  float v = in[((size_t)(n * 16 + c) * 256 + (y >> 2)) * 256 + (x >> 2)];
  out[i] = v < 0.f ? 0.f : v;
}

// ---------------------------------------------------------------------------
// Per-pixel 5x5 dynamic conv + residual, one image, one row-strip:
// out[y,x] = h[y,x] + sum_{kw,kh} h_pad[y+kh-2, x+kw-2] * ker[kw*5+kh, y, x]
// ker holds rows [ky0, ky0+krows) of the image (channel stride krows*1024).
// ---------------------------------------------------------------------------
__global__ __launch_bounds__(256) void pixel_conv_add_k(
    const float* __restrict__ h,    // full image (1024,1024)
    const float* __restrict__ ker,  // (25, krows, 1024)
    float* __restrict__ out,        // full image (1024,1024)
    int ky0, int krows)
{
  const int tx = threadIdx.x & 15, ty = threadIdx.x >> 4;
  const int x0 = blockIdx.x * 16;
  const int y0 = ky0 + blockIdx.y * 16;

  __shared__ float tile[20][21];
  for (int t = threadIdx.x; t < 20 * 20; t += 256) {
    int r = t / 20, c = t - r * 20;
    int yy = y0 + r - 2, xx = x0 + c - 2;
    float v = 0.f;
    if (yy >= 0 && yy < 1024 && xx >= 0 && xx < 1024) v = h[(size_t)yy * 1024 + xx];
    tile[r][c] = v;
  }
  __syncthreads();

  const int x = x0 + tx, y = y0 + ty;
  float acc = tile[ty + 2][tx + 2];            // residual h
  const size_t kpix = (size_t)(y - ky0) * 1024 + x;
#pragma unroll
  for (int kw = 0; kw < 5; ++kw) {
#pragma unroll
    for (int kh = 0; kh < 5; ++kh) {
      float kv = ker[(size_t)(kw * 5 + kh) * krows * 1024 + kpix];
      acc = fmaf(tile[ty + kh][tx + kw], kv, acc);
    }
  }
  out[(size_t)y * 1024 + x] = acc;
}

// ---------------------------------------------------------------------------
// Launch. Workspace (adaptive to ws_size):
//   Hs: 8 MiB  — shuffled h, both images, persists
//   A : max(32ch*(S+6)*1024*4, 16.8 MB)  — z1/z3 strip buf; encoder ping (2 img)
//   B : max(64ch*(S+4)*1024*4, 33.6 MB)  — z2/z4 strip buf; encoder pong (2 img)
// S = largest of {1024,512,256,128,64} fitting ws_size.
// Encoder/decoder batches BOTH images per dispatch.
// z-branch runs per image in row strips of height S with halo-recompute
// (identical numerics to full-image conv).
// ---------------------------------------------------------------------------
extern "C" void kernel_launch(void* const* d_in, const int* in_sizes, int n_in,
                              void* d_out, int out_size, void* d_ws, size_t ws_size,
                              hipStream_t stream) {
  const float* x    = (const float*)d_in[0];
  const float* w_e1 = (const float*)d_in[1];
  const float* w_e2 = (const float*)d_in[2];
  const float* w_e3 = (const float*)d_in[3];
  const float* w_d1 = (const float*)d_in[4];
  const float* w_d2 = (const float*)d_in[5];
  const float* w_k1 = (const float*)d_in[6];
  const float* w_k2 = (const float*)d_in[7];
  const float* w_k3 = (const float*)d_in[8];
  const float* w_k4 = (const float*)d_in[9];

  const size_t HS_SZ = 8388608;                 // 2 * 1024*1024 * 4
  const size_t AMIN  = 16777216;                // 2 img * 32ch @256²
  const size_t BMIN  = 33554432;                // 2 img * 64ch @256²

  int S = 64;
  {
    const int cand[5] = {1024, 512, 256, 128, 64};
    for (int i = 0; i < 5; ++i) {
      int s = cand[i];
      size_t a = 32ull * (size_t)(s + 6) * 1024 * 4; if (a < AMIN) a = AMIN;
      size_t b = 64ull * (size_t)(s + 4) * 1024 * 4; if (b < BMIN) b = BMIN;
      if (HS_SZ + a + b <= ws_size) { S = s; break; }
    }
  }
  size_t A_SZ = 32ull * (size_t)(S + 6) * 1024 * 4; if (A_SZ < AMIN) A_SZ = AMIN;

  char* ws = (char*)d_ws;
  float* Hs = (float*)(ws);
  float* A  = (float*)(ws + HS_SZ);
  float* B  = (float*)(ws + HS_SZ + A_SZ);
  float* outp = (float*)d_out;

  dim3 blk(256);

  // ---- encoder/decoder @256², both images per dispatch, ping-pong A<->B ----
  // P=4 -> TH=16. grid: (256/64, 256/16, 2*NCB)
  conv3x3_relu_k<1, 16, 16, 4, 256><<<dim3(4, 16, 2), blk, 0, stream>>>(x, w_e1, B, 0, 256, 0, 256);
  conv3x3_relu_k<16, 32, 16, 4, 256><<<dim3(4, 16, 4), blk, 0, stream>>>(B, w_e2, A, 0, 256, 0, 256);
  conv3x3_relu_k<32, 64, 16, 4, 256><<<dim3(4, 16, 8), blk, 0, stream>>>(A, w_e3, B, 0, 256, 0, 256);
  conv3x3_relu_k<64, 32, 16, 4, 256><<<dim3(4, 16, 4), blk, 0, stream>>>(B, w_d1, A, 0, 256, 0, 256);
  conv3x3_relu_k<32, 16, 16, 4, 256><<<dim3(4, 16, 2), blk, 0, stream>>>(A, w_d2, B, 0, 256, 0, 256);
  pixel_shuffle_relu_k<<<dim3(8192), blk, 0, stream>>>(B, Hs);

  // ---- kernel-prediction branch + dynamic conv, per image, row strips ----
  const int nstr = 1024 / S;
  for (int n = 0; n < 2; ++n) {
    const float* himg = Hs + (size_t)n * 1048576;
    float* outn = outp + (size_t)n * 1048576;
    for (int s = 0; s < nstr; ++s) {
      const int r0 = s * S, r1 = r0 + S;
      const int z1y0 = (r0 - 3 > 0) ? r0 - 3 : 0;
      const int z1r  = ((r1 + 3 < 1024) ? r1 + 3 : 1024) - z1y0;
      const int z2y0 = (r0 - 2 > 0) ? r0 - 2 : 0;
      const int z2r  = ((r1 + 2 < 1024) ? r1 + 2 : 1024) - z2y0;
      const int z3y0 = (r0 - 1 > 0) ? r0 - 1 : 0;
      const int z3r  = ((r1 + 1 < 1024) ? r1 + 1 : 1024) - z3y0;
      const int g1 = (z1r + 15) / 16, g2 = (z2r + 15) / 16, g3 = (z3r + 15) / 16;

      conv3x3_relu_k<1, 32, 16, 4, 1024><<<dim3(16, g1, 2), blk, 0, stream>>>(
          himg, w_k1, A, 0, 1024, z1y0, z1r);
      conv3x3_relu_k<32, 64, 16, 4, 1024><<<dim3(16, g2, 4), blk, 0, stream>>>(
          A, w_k2, B, z1y0, z1r, z2y0, z2r);
      conv3x3_relu_k<64, 32, 16, 4, 1024><<<dim3(16, g3, 2), blk, 0, stream>>>(
          B, w_k3, A, z2y0, z2r, z3y0, z3r);
      conv3x3_relu_k<32, 25, 25, 4, 1024><<<dim3(16, S / 16, 1), blk, 0, stream>>>(
          A, w_k4, B, z3y0, z3r, r0, S);
      pixel_conv_add_k<<<dim3(64, S / 16), blk, 0, stream>>>(
          himg, B, outn, r0, S);
    }
  }
}